// Round 1
// baseline (7150.811 us; speedup 1.0000x reference)
//
#include <hip/hip_runtime.h>
#include <math.h>

#define T_STEPS 64
#define BATCH   128
#define TBTOT   8192

// ---------------- workspace layout (float offsets) ----------------
static const size_t OFF_CONV3  = 0;              // [8192][1568]
static const size_t OFF_IMGH   = 12845056;       // [8192][256]
static const size_t OFF_LANGIN = 14942208;       // [8192][32]
static const size_t OFF_ENCXW  = 15204352;       // [8192][1024]
static const size_t OFF_ENCHS  = 23592960;       // [8192][256]
static const size_t OFF_LANGH  = 25690112;       // [8192][32]
static const size_t OFF_HIDDEN = 25952256;       // [8192][288]
static const size_t OFF_MEMXW  = 28311552;       // [8192][4096]
static const size_t OFF_MEMHS  = 61865984;       // [8192][1024]
static const size_t OFF_HBUFE  = 70254592;       // [2][128][256]
static const size_t OFF_HBUFM  = 70320128;       // [2][128][1024]
static const size_t OFF_ENCBC  = 70582272;       // [1024]
static const size_t OFF_MEMBC  = 70583296;       // [4096]
static const size_t OFF_HEADW  = 70587392;       // [16][1024]
static const size_t OFF_HEADB  = 70603776;       // [16]
static const size_t OFF_BARS   = 70603792;       // 64 uints

__device__ __forceinline__ float sigm(float x) { return 1.0f / (1.0f + expf(-x)); }

// -------- device-scope grid barrier (monotone counter; zeroed by prep each launch) --------
__device__ __forceinline__ void gridbar(unsigned* cnt, unsigned target) {
    __syncthreads();
    if (threadIdx.x == 0) {
        __threadfence();  // release all prior global writes
        __hip_atomic_fetch_add(cnt, 1u, __ATOMIC_RELEASE, __HIP_MEMORY_SCOPE_AGENT);
        while (__hip_atomic_load(cnt, __ATOMIC_ACQUIRE, __HIP_MEMORY_SCOPE_AGENT) < target) {
            __builtin_amdgcn_s_sleep(1);
        }
    }
    __syncthreads();
}

// ---------------- prep: combined biases, head weights, zero barriers ----------------
__global__ void prep_kernel(const float* __restrict__ enc_bih, const float* __restrict__ enc_bhh,
                            const float* __restrict__ mem_bih, const float* __restrict__ mem_bhh,
                            const float* __restrict__ actor_w, const float* __restrict__ actor_b,
                            const float* __restrict__ critic_w, const float* __restrict__ critic_b,
                            float* __restrict__ enc_bc, float* __restrict__ mem_bc,
                            float* __restrict__ head_w, float* __restrict__ head_b,
                            unsigned* __restrict__ bars) {
    int g = blockIdx.x * 256 + threadIdx.x;
    if (g < 1024)  enc_bc[g] = enc_bih[g] + enc_bhh[g];
    if (g < 4096)  mem_bc[g] = mem_bih[g] + mem_bhh[g];
    if (g < 16384) { int j = g >> 10, k = g & 1023; head_w[g] = (j < 15) ? actor_w[j * 1024 + k] : critic_w[k]; }
    if (g < 16)    head_b[g] = (g < 15) ? actor_b[g] : critic_b[0];
    if (g < 64)    bars[g] = 0u;
}

// ---------------- fused conv stack, one block per image ----------------
__global__ __launch_bounds__(256) void conv_kernel(const float* __restrict__ x,
        const float* __restrict__ w1, const float* __restrict__ b1,
        const float* __restrict__ w2, const float* __restrict__ b2,
        const float* __restrict__ w3, const float* __restrict__ b3,
        float* __restrict__ out) {
    __shared__ float arena[16384];   // exactly 64 KB
    const int t = threadIdx.x;
    const size_t img = blockIdx.x;

    // P0: out1 @0 (1936) | w1 @1936 (1296) | b1 @3232 (16) | img @3248 (9801)
    float* s_out1 = arena;
    float* s_w1   = arena + 1936;
    float* s_b1   = arena + 3232;
    float* s_img  = arena + 3248;
    const float* xi = x + img * 9801;
    for (int i = t; i < 9801; i += 256) s_img[i] = xi[i] * (1.0f / 255.0f);
    for (int i = t; i < 1296; i += 256) s_w1[i] = w1[i];
    if (t < 16) s_b1[t] = b1[t];
    __syncthreads();

    // conv1: 9x9 stride 9 (non-overlapping), tasks (c,i) = 16*11
    if (t < 176) {
        int c = t / 11, i = t - c * 11;
        float accr[11];
        #pragma unroll
        for (int j = 0; j < 11; ++j) accr[j] = s_b1[c];
        for (int ky = 0; ky < 9; ++ky) {
            const float* irow = s_img + (i * 9 + ky) * 99;
            const float* wrow = s_w1 + c * 81 + ky * 9;
            for (int kx = 0; kx < 9; ++kx) {
                float wv = wrow[kx];
                #pragma unroll
                for (int j = 0; j < 11; ++j) accr[j] += wv * irow[j * 9 + kx];
            }
        }
        #pragma unroll
        for (int j = 0; j < 11; ++j) s_out1[c * 121 + i * 11 + j] = fmaxf(accr[j], 0.0f);
    }
    __syncthreads();

    // P1: out1 @0 | w2 @1936 (4608) | b2 @6544 (32) | out2 @13792 (2592)
    float* s_w2   = arena + 1936;
    float* s_b2   = arena + 6544;
    float* s_out2 = arena + 13792;
    for (int i = t; i < 4608; i += 256) s_w2[i] = w2[i];
    if (t < 32) s_b2[t] = b2[t];
    __syncthreads();

    // conv2: 3x3, tasks (c,i) = 32*9 = 288
    for (int rr = 0; rr < 2; ++rr) {
        int task = rr * 256 + t;
        if (task < 288) {
            int c = task / 9, i = task - c * 9;
            float accr[9];
            #pragma unroll
            for (int j = 0; j < 9; ++j) accr[j] = s_b2[c];
            for (int ic = 0; ic < 16; ++ic) {
                const float* ibase = s_out1 + ic * 121 + i * 11;
                const float* wbase = s_w2 + (c * 16 + ic) * 9;
                #pragma unroll
                for (int ky = 0; ky < 3; ++ky) {
                    const float* irow = ibase + ky * 11;
                    #pragma unroll
                    for (int kx = 0; kx < 3; ++kx) {
                        float wv = wbase[ky * 3 + kx];
                        #pragma unroll
                        for (int j = 0; j < 9; ++j) accr[j] += wv * irow[j + kx];
                    }
                }
            }
            #pragma unroll
            for (int j = 0; j < 9; ++j) s_out2[c * 81 + i * 9 + j] = fmaxf(accr[j], 0.0f);
        }
    }
    __syncthreads();

    // P2: w3 @0 (9216) | b3 @9216 (32) | out3 @9248 (1568) | out2 stays @13792
    float* s_w3   = arena;
    float* s_b3   = arena + 9216;
    float* s_out3 = arena + 9248;
    for (int i = t; i < 9216; i += 256) s_w3[i] = w3[i];
    if (t < 32) s_b3[t] = b3[t];
    __syncthreads();

    // conv3: 3x3, tasks (c,i) = 32*7 = 224
    if (t < 224) {
        int c = t / 7, i = t - c * 7;
        float accr[7];
        #pragma unroll
        for (int j = 0; j < 7; ++j) accr[j] = s_b3[c];
        for (int ic = 0; ic < 32; ++ic) {
            const float* ibase = s_out2 + ic * 81 + i * 9;
            const float* wbase = s_w3 + (c * 32 + ic) * 9;
            #pragma unroll
            for (int ky = 0; ky < 3; ++ky) {
                const float* irow = ibase + ky * 9;
                #pragma unroll
                for (int kx = 0; kx < 3; ++kx) {
                    float wv = wbase[ky * 3 + kx];
                    #pragma unroll
                    for (int j = 0; j < 7; ++j) accr[j] += wv * irow[j + kx];
                }
            }
        }
        #pragma unroll
        for (int j = 0; j < 7; ++j) s_out3[c * 49 + i * 7 + j] = fmaxf(accr[j], 0.0f);
    }
    __syncthreads();
    float* og = out + img * 1568;
    for (int i = t; i < 1568; i += 256) og[i] = s_out3[i];
}

// ---------------- generic tiled GEMM: C[M,N] = act(A[M,K] @ W[N,K]^T + bias) ----------------
// 64 threads, BM=BN=64, BK=32, 8x8 register tile. M%64==0, K%32==0; N guarded.
template <bool RELU>
__global__ __launch_bounds__(64) void gemm64(const float* __restrict__ A, const float* __restrict__ W,
                                             const float* __restrict__ bias, float* __restrict__ C,
                                             int M, int N, int K) {
    __shared__ float At[32][68];
    __shared__ float Wt[32][68];
    const int m0 = blockIdx.x * 64, n0 = blockIdx.y * 64;
    const int t = threadIdx.x;
    const int tx = t & 7, ty = t >> 3;
    float acc[8][8] = {};
    for (int kc = 0; kc < K; kc += 32) {
        #pragma unroll
        for (int i = 0; i < 8; ++i) {
            int e = t + i * 64;
            int row = e >> 3, c4 = (e & 7) * 4;
            float4 v = *(const float4*)&A[(size_t)(m0 + row) * K + kc + c4];
            At[c4 + 0][row] = v.x; At[c4 + 1][row] = v.y; At[c4 + 2][row] = v.z; At[c4 + 3][row] = v.w;
            int n = n0 + row;
            float4 wv = make_float4(0.f, 0.f, 0.f, 0.f);
            if (n < N) wv = *(const float4*)&W[(size_t)n * K + kc + c4];
            Wt[c4 + 0][row] = wv.x; Wt[c4 + 1][row] = wv.y; Wt[c4 + 2][row] = wv.z; Wt[c4 + 3][row] = wv.w;
        }
        __syncthreads();
        #pragma unroll
        for (int kk = 0; kk < 32; ++kk) {
            float4 a0 = *(const float4*)&At[kk][ty * 8];
            float4 a1 = *(const float4*)&At[kk][ty * 8 + 4];
            float4 b0 = *(const float4*)&Wt[kk][tx * 8];
            float4 b1 = *(const float4*)&Wt[kk][tx * 8 + 4];
            float a[8] = {a0.x, a0.y, a0.z, a0.w, a1.x, a1.y, a1.z, a1.w};
            float b[8] = {b0.x, b0.y, b0.z, b0.w, b1.x, b1.y, b1.z, b1.w};
            #pragma unroll
            for (int i = 0; i < 8; ++i)
                #pragma unroll
                for (int j = 0; j < 8; ++j) acc[i][j] += a[i] * b[j];
        }
        __syncthreads();
    }
    #pragma unroll
    for (int i = 0; i < 8; ++i) {
        int m = m0 + ty * 8 + i;
        #pragma unroll
        for (int j = 0; j < 8; ++j) {
            int n = n0 + tx * 8 + j;
            if (n < N) {
                float v = acc[i][j] + bias[n];
                if (RELU) v = fmaxf(v, 0.0f);
                C[(size_t)m * N + n] = v;
            }
        }
    }
}

// ---------------- embedding ----------------
__global__ void embed_kernel(const int* __restrict__ lang, const float* __restrict__ emb,
                             float* __restrict__ out) {
    int g = blockIdx.x * 256 + threadIdx.x;
    if (g < TBTOT * 32) { int r = g >> 5, c = g & 31; out[g] = emb[lang[r] * 32 + c]; }
}

// ---------------- concat [img_hidden(256) | lang_hidden(32)] ----------------
__global__ void concat_kernel(const float* __restrict__ img_h, const float* __restrict__ lang_h,
                              float* __restrict__ out) {
    int r = blockIdx.x, c = threadIdx.x;
    out[r * 288 + c] = (c < 256) ? img_h[r * 256 + c] : lang_h[r * 32 + (c - 256)];
}

// ---------------- persistent masked LSTM scan ----------------
// grid (H/16, 4): blockIdx.x = j-tile (j-tile-major so each XCD's Whh slice fits its L2),
// blockIdx.y = b-tile. Block covers 32 batch x 16 hidden cols; thread owns 2 (b,j) cells,
// keeps c in registers; h double-buffered in ws; one grid barrier per step.
template <int H, bool PER_ENV_MASK>
__global__ __launch_bounds__(256) void lstm_scan_kernel(
        const float* __restrict__ xw,   // [T*B][4H]  (x@Wih^T + bih + bhh)
        const float* __restrict__ Whh,  // [4H][H]
        const float* __restrict__ done, // [T*B]
        const float* __restrict__ h0, const float* __restrict__ c0,
        float* __restrict__ hbuf,       // [2][B][H]
        float* __restrict__ hs,         // [T*B][H]
        unsigned* __restrict__ bar_cnt, unsigned nblk) {
    __shared__ float wl[64][36];
    __shared__ float hl[32][36];
    const int t = threadIdx.x;
    const int jl = t & 15, bl = t >> 4;
    const int j0 = blockIdx.x * 16;
    const int b0 = blockIdx.y * 32;
    const int b_a = b0 + bl, b_b = b0 + bl + 16;
    const int jg = j0 + jl;

    float c_reg[2];
    c_reg[0] = c0[b_a * H + jg];
    c_reg[1] = c0[b_b * H + jg];
    hbuf[b_a * H + jg] = h0[b_a * H + jg];
    hbuf[b_b * H + jg] = h0[b_b * H + jg];
    unsigned bar = 1;
    gridbar(bar_cnt, nblk * bar); ++bar;

    int cur = 0;
    for (int st = 0; st < T_STEPS; ++st) {
        float m_a, m_b_;
        if (PER_ENV_MASK) {
            m_a  = 1.0f - done[st * BATCH + b_a];
            m_b_ = 1.0f - done[st * BATCH + b_b];
        } else {
            float m = 1.0f - done[st];
            m_a = m; m_b_ = m;
        }
        float acc[2][4] = {};
        const float* hsrc = hbuf + (size_t)cur * (BATCH * H);
        for (int kc = 0; kc < H; kc += 32) {
            #pragma unroll
            for (int i = 0; i < 2; ++i) {   // stage Whh tile: 64 rows x 32 cols
                int e4 = t + i * 256;
                int row = e4 >> 3, c4 = (e4 & 7) * 4;
                int q = row >> 4, jr = row & 15;
                float4 v = *(const float4*)&Whh[(size_t)(q * H + j0 + jr) * H + kc + c4];
                wl[row][c4 + 0] = v.x; wl[row][c4 + 1] = v.y; wl[row][c4 + 2] = v.z; wl[row][c4 + 3] = v.w;
            }
            {   // stage masked h tile: 32 rows x 32 cols
                int bs = t >> 3, k4 = (t & 7) * 4;
                float msk = PER_ENV_MASK ? (1.0f - done[st * BATCH + b0 + bs]) : m_a;
                float4 hv = *(const float4*)&hsrc[(size_t)(b0 + bs) * H + kc + k4];
                hl[bs][k4 + 0] = hv.x * msk; hl[bs][k4 + 1] = hv.y * msk;
                hl[bs][k4 + 2] = hv.z * msk; hl[bs][k4 + 3] = hv.w * msk;
            }
            __syncthreads();
            #pragma unroll
            for (int kk = 0; kk < 32; kk += 2) {
                float2 ha = *(const float2*)&hl[bl][kk];
                float2 hb = *(const float2*)&hl[bl + 16][kk];
                #pragma unroll
                for (int q = 0; q < 4; ++q) {
                    float2 w = *(const float2*)&wl[q * 16 + jl][kk];
                    acc[0][q] += ha.x * w.x + ha.y * w.y;
                    acc[1][q] += hb.x * w.x + hb.y * w.y;
                }
            }
            __syncthreads();
        }
        #pragma unroll
        for (int e = 0; e < 2; ++e) {
            int b = (e == 0) ? b_a : b_b;
            float m = (e == 0) ? m_a : m_b_;
            const float* xr = xw + (size_t)(st * BATCH + b) * (4 * H);
            float gi = acc[e][0] + xr[jg];
            float gf = acc[e][1] + xr[H + jg];
            float gg = acc[e][2] + xr[2 * H + jg];
            float go = acc[e][3] + xr[3 * H + jg];
            float c = sigm(gf) * (c_reg[e] * m) + sigm(gi) * tanhf(gg);
            float h = sigm(go) * tanhf(c);
            c_reg[e] = c;
            hbuf[(size_t)(cur ^ 1) * (BATCH * H) + b * H + jg] = h;
            hs[(size_t)(st * BATCH + b) * H + jg] = h;
        }
        gridbar(bar_cnt, nblk * bar); ++bar;
        cur ^= 1;
    }
}

extern "C" void kernel_launch(void* const* d_in, const int* in_sizes, int n_in,
                              void* d_out, int out_size, void* d_ws, size_t ws_size,
                              hipStream_t stream) {
    const float* x_img    = (const float*)d_in[0];
    const int*   x_lang   = (const int*)d_in[1];
    const float* done     = (const float*)d_in[2];
    const float* enc_h0   = (const float*)d_in[3];
    const float* enc_c0   = (const float*)d_in[4];
    const float* mem_h0   = (const float*)d_in[5];
    const float* mem_c0   = (const float*)d_in[6];
    const float* emb      = (const float*)d_in[7];
    const float* conv1_w  = (const float*)d_in[8];
    const float* conv1_b  = (const float*)d_in[9];
    const float* conv2_w  = (const float*)d_in[10];
    const float* conv2_b  = (const float*)d_in[11];
    const float* conv3_w  = (const float*)d_in[12];
    const float* conv3_b  = (const float*)d_in[13];
    const float* fc_w     = (const float*)d_in[14];
    const float* fc_b     = (const float*)d_in[15];
    const float* enc_Wih  = (const float*)d_in[16];
    const float* enc_Whh  = (const float*)d_in[17];
    const float* enc_bih  = (const float*)d_in[18];
    const float* enc_bhh  = (const float*)d_in[19];
    const float* lemb_w   = (const float*)d_in[20];
    const float* lemb_b   = (const float*)d_in[21];
    const float* mem_Wih  = (const float*)d_in[22];
    const float* mem_Whh  = (const float*)d_in[23];
    const float* mem_bih  = (const float*)d_in[24];
    const float* mem_bhh  = (const float*)d_in[25];
    const float* actor_w  = (const float*)d_in[26];
    const float* actor_b  = (const float*)d_in[27];
    const float* critic_w = (const float*)d_in[28];
    const float* critic_b = (const float*)d_in[29];

    float* ws = (float*)d_ws;
    float* conv3_flat = ws + OFF_CONV3;
    float* img_hidden = ws + OFF_IMGH;
    float* lang_in    = ws + OFF_LANGIN;
    float* enc_xW     = ws + OFF_ENCXW;
    float* enc_hs     = ws + OFF_ENCHS;
    float* lang_h     = ws + OFF_LANGH;
    float* hidden     = ws + OFF_HIDDEN;
    float* mem_xW     = ws + OFF_MEMXW;
    float* mem_hs     = ws + OFF_MEMHS;
    float* hbuf_e     = ws + OFF_HBUFE;
    float* hbuf_m     = ws + OFF_HBUFM;
    float* enc_bc     = ws + OFF_ENCBC;
    float* mem_bc     = ws + OFF_MEMBC;
    float* head_w     = ws + OFF_HEADW;
    float* head_b     = ws + OFF_HEADB;
    unsigned* bars    = (unsigned*)(ws + OFF_BARS);

    prep_kernel<<<64, 256, 0, stream>>>(enc_bih, enc_bhh, mem_bih, mem_bhh,
                                        actor_w, actor_b, critic_w, critic_b,
                                        enc_bc, mem_bc, head_w, head_b, bars);
    conv_kernel<<<TBTOT, 256, 0, stream>>>(x_img, conv1_w, conv1_b, conv2_w, conv2_b,
                                           conv3_w, conv3_b, conv3_flat);
    gemm64<true><<<dim3(128, 4), 64, 0, stream>>>(conv3_flat, fc_w, fc_b, img_hidden, TBTOT, 256, 1568);
    embed_kernel<<<1024, 256, 0, stream>>>(x_lang, emb, lang_in);
    gemm64<false><<<dim3(128, 16), 64, 0, stream>>>(lang_in, enc_Wih, enc_bc, enc_xW, TBTOT, 1024, 32);
    lstm_scan_kernel<256, false><<<dim3(16, 4), 256, 0, stream>>>(
        enc_xW, enc_Whh, done, enc_h0, enc_c0, hbuf_e, enc_hs, bars + 0, 64u);
    gemm64<true><<<dim3(128, 1), 64, 0, stream>>>(enc_hs, lemb_w, lemb_b, lang_h, TBTOT, 32, 256);
    concat_kernel<<<TBTOT, 288, 0, stream>>>(img_hidden, lang_h, hidden);
    gemm64<false><<<dim3(128, 64), 64, 0, stream>>>(hidden, mem_Wih, mem_bc, mem_xW, TBTOT, 4096, 288);
    lstm_scan_kernel<1024, true><<<dim3(64, 4), 256, 0, stream>>>(
        mem_xW, mem_Whh, done, mem_h0, mem_c0, hbuf_m, mem_hs, bars + 8, 256u);
    gemm64<false><<<dim3(128, 1), 64, 0, stream>>>(mem_hs, head_w, head_b, (float*)d_out, TBTOT, 16, 1024);
}

// Round 2
// 4534.759 us; speedup vs baseline: 1.5769x; 1.5769x over previous
//
#include <hip/hip_runtime.h>
#include <math.h>

#define T_STEPS 64
#define BATCH   128
#define TBTOT   8192

typedef __attribute__((ext_vector_type(8))) short bf16x8;
typedef __attribute__((ext_vector_type(4))) float f32x4;

// ---------------- workspace layout (float offsets) ----------------
// Region [0, 12845056) holds conv3 activations first, then (after the fc GEMM
// consumes them) is reused for the LSTM split-weight fragments + h buffers.
static const size_t OFF_CONV3  = 0;              // [8192][1568] f32 (phase 1)
static const size_t OFF_MWFHI  = 0;              // [4096*1024] bf16  (phase 2)
static const size_t OFF_MWFLO  = 2097152;        // [4096*1024] bf16
static const size_t OFF_EWFHI  = 4194304;        // [1024*256] bf16
static const size_t OFF_EWFLO  = 4325376;        // [1024*256] bf16
static const size_t OFF_HBMHI  = 4456448;        // [2][128][1024] bf16
static const size_t OFF_HBMLO  = 4587520;        // [2][128][1024] bf16
static const size_t OFF_HBEHI  = 4718592;        // [2][128][256] bf16
static const size_t OFF_HBELO  = 4734976;        // [2][128][256] bf16
static const size_t OFF_IMGH   = 12845056;       // [8192][256]
static const size_t OFF_LANGIN = 14942208;       // [8192][32]
static const size_t OFF_ENCXW  = 15204352;       // [8192][1024]
static const size_t OFF_ENCHS  = 23592960;       // [8192][256]
static const size_t OFF_LANGH  = 25690112;       // [8192][32]
static const size_t OFF_HIDDEN = 25952256;       // [8192][288]
static const size_t OFF_MEMXW  = 28311552;       // [8192][4096]
static const size_t OFF_MEMHS  = 61865984;       // [8192][1024]
static const size_t OFF_ENCBC  = 70582272;       // [1024]
static const size_t OFF_MEMBC  = 70583296;       // [4096]
static const size_t OFF_HEADW  = 70587392;       // [16][1024]
static const size_t OFF_HEADB  = 70603776;       // [16]
static const size_t OFF_BARS   = 70603792;       // 64 uints

__device__ __forceinline__ float fast_sigm(float x) { return 1.0f / (1.0f + __expf(-x)); }
__device__ __forceinline__ float fast_tanh(float x) { return 2.0f / (1.0f + __expf(-2.0f * x)) - 1.0f; }

__device__ __forceinline__ short f32_to_bf16_rne(float x) {
    unsigned u = __float_as_uint(x);
    unsigned r = (u + 0x7fffu + ((u >> 16) & 1u)) >> 16;
    return (short)r;
}
__device__ __forceinline__ float bf16s_to_f32(short s) {
    return __uint_as_float(((unsigned)(unsigned short)s) << 16);
}

// -------- device-scope grid barrier (monotone counter; zeroed by prep each launch) --------
__device__ __forceinline__ void gridbar(unsigned* cnt, unsigned target) {
    __syncthreads();
    if (threadIdx.x == 0) {
        __threadfence();  // release all prior global writes
        __hip_atomic_fetch_add(cnt, 1u, __ATOMIC_RELEASE, __HIP_MEMORY_SCOPE_AGENT);
        while (__hip_atomic_load(cnt, __ATOMIC_ACQUIRE, __HIP_MEMORY_SCOPE_AGENT) < target) {
            __builtin_amdgcn_s_sleep(1);
        }
    }
    __syncthreads();
}

// ---------------- prep: combined biases, head weights, zero barriers ----------------
__global__ void prep_kernel(const float* __restrict__ enc_bih, const float* __restrict__ enc_bhh,
                            const float* __restrict__ mem_bih, const float* __restrict__ mem_bhh,
                            const float* __restrict__ actor_w, const float* __restrict__ actor_b,
                            const float* __restrict__ critic_w, const float* __restrict__ critic_b,
                            float* __restrict__ enc_bc, float* __restrict__ mem_bc,
                            float* __restrict__ head_w, float* __restrict__ head_b,
                            unsigned* __restrict__ bars) {
    int g = blockIdx.x * 256 + threadIdx.x;
    if (g < 1024)  enc_bc[g] = enc_bih[g] + enc_bhh[g];
    if (g < 4096)  mem_bc[g] = mem_bih[g] + mem_bhh[g];
    if (g < 16384) { int j = g >> 10, k = g & 1023; head_w[g] = (j < 15) ? actor_w[j * 1024 + k] : critic_w[k]; }
    if (g < 16)    head_b[g] = (g < 15) ? actor_b[g] : critic_b[0];
    if (g < 64)    bars[g] = 0u;
}

// ---------------- split Whh into MFMA-fragment-ordered bf16 hi/lo ----------------
// Fragment layout: idx = (((q*(H/16)+jt)*(H/32)+ks)*64 + lane)*8 + e
//   n = q*H + jt*16 + (lane&15);  k = ks*32 + (lane>>4)*8 + e
__global__ void split_frag_kernel(const float* __restrict__ W, short* __restrict__ hi,
                                  short* __restrict__ lo, int H) {
    size_t f = (size_t)blockIdx.x * 256 + threadIdx.x;
    size_t total = (size_t)4 * H * H;
    if (f >= total) return;
    int e    = (int)(f & 7);
    int lane = (int)((f >> 3) & 63);
    size_t rest = f >> 9;
    int nks = H >> 5;
    int ks  = (int)(rest % nks);
    int qjt = (int)(rest / nks);
    int njt = H >> 4;
    int qq = qjt / njt, jt = qjt - qq * njt;
    int n = qq * H + jt * 16 + (lane & 15);
    int k = ks * 32 + (lane >> 4) * 8 + e;
    float w = W[(size_t)n * H + k];
    short a = f32_to_bf16_rne(w);
    short b = f32_to_bf16_rne(w - bf16s_to_f32(a));
    hi[f] = a; lo[f] = b;
}

// ---------------- fused conv stack, one block per image ----------------
__global__ __launch_bounds__(256) void conv_kernel(const float* __restrict__ x,
        const float* __restrict__ w1, const float* __restrict__ b1,
        const float* __restrict__ w2, const float* __restrict__ b2,
        const float* __restrict__ w3, const float* __restrict__ b3,
        float* __restrict__ out) {
    __shared__ float arena[16384];
    const int t = threadIdx.x;
    const size_t img = blockIdx.x;

    float* s_out1 = arena;
    float* s_w1   = arena + 1936;
    float* s_b1   = arena + 3232;
    float* s_img  = arena + 3248;
    const float* xi = x + img * 9801;
    for (int i = t; i < 9801; i += 256) s_img[i] = xi[i] * (1.0f / 255.0f);
    for (int i = t; i < 1296; i += 256) s_w1[i] = w1[i];
    if (t < 16) s_b1[t] = b1[t];
    __syncthreads();

    if (t < 176) {
        int c = t / 11, i = t - c * 11;
        float accr[11];
        #pragma unroll
        for (int j = 0; j < 11; ++j) accr[j] = s_b1[c];
        for (int ky = 0; ky < 9; ++ky) {
            const float* irow = s_img + (i * 9 + ky) * 99;
            const float* wrow = s_w1 + c * 81 + ky * 9;
            for (int kx = 0; kx < 9; ++kx) {
                float wv = wrow[kx];
                #pragma unroll
                for (int j = 0; j < 11; ++j) accr[j] += wv * irow[j * 9 + kx];
            }
        }
        #pragma unroll
        for (int j = 0; j < 11; ++j) s_out1[c * 121 + i * 11 + j] = fmaxf(accr[j], 0.0f);
    }
    __syncthreads();

    float* s_w2   = arena + 1936;
    float* s_b2   = arena + 6544;
    float* s_out2 = arena + 13792;
    for (int i = t; i < 4608; i += 256) s_w2[i] = w2[i];
    if (t < 32) s_b2[t] = b2[t];
    __syncthreads();

    for (int rr = 0; rr < 2; ++rr) {
        int task = rr * 256 + t;
        if (task < 288) {
            int c = task / 9, i = task - c * 9;
            float accr[9];
            #pragma unroll
            for (int j = 0; j < 9; ++j) accr[j] = s_b2[c];
            for (int ic = 0; ic < 16; ++ic) {
                const float* ibase = s_out1 + ic * 121 + i * 11;
                const float* wbase = s_w2 + (c * 16 + ic) * 9;
                #pragma unroll
                for (int ky = 0; ky < 3; ++ky) {
                    const float* irow = ibase + ky * 11;
                    #pragma unroll
                    for (int kx = 0; kx < 3; ++kx) {
                        float wv = wbase[ky * 3 + kx];
                        #pragma unroll
                        for (int j = 0; j < 9; ++j) accr[j] += wv * irow[j + kx];
                    }
                }
            }
            #pragma unroll
            for (int j = 0; j < 9; ++j) s_out2[c * 81 + i * 9 + j] = fmaxf(accr[j], 0.0f);
        }
    }
    __syncthreads();

    float* s_w3   = arena;
    float* s_b3   = arena + 9216;
    float* s_out3 = arena + 9248;
    for (int i = t; i < 9216; i += 256) s_w3[i] = w3[i];
    if (t < 32) s_b3[t] = b3[t];
    __syncthreads();

    if (t < 224) {
        int c = t / 7, i = t - c * 7;
        float accr[7];
        #pragma unroll
        for (int j = 0; j < 7; ++j) accr[j] = s_b3[c];
        for (int ic = 0; ic < 32; ++ic) {
            const float* ibase = s_out2 + ic * 81 + i * 9;
            const float* wbase = s_w3 + (c * 32 + ic) * 9;
            #pragma unroll
            for (int ky = 0; ky < 3; ++ky) {
                const float* irow = ibase + ky * 9;
                #pragma unroll
                for (int kx = 0; kx < 3; ++kx) {
                    float wv = wbase[ky * 3 + kx];
                    #pragma unroll
                    for (int j = 0; j < 7; ++j) accr[j] += wv * irow[j + kx];
                }
            }
        }
        #pragma unroll
        for (int j = 0; j < 7; ++j) s_out3[c * 49 + i * 7 + j] = fmaxf(accr[j], 0.0f);
    }
    __syncthreads();
    float* og = out + img * 1568;
    for (int i = t; i < 1568; i += 256) og[i] = s_out3[i];
}

// ---------------- generic tiled GEMM: C[M,N] = act(A[M,K] @ W[N,K]^T + bias) ----------------
template <bool RELU>
__global__ __launch_bounds__(64) void gemm64(const float* __restrict__ A, const float* __restrict__ W,
                                             const float* __restrict__ bias, float* __restrict__ C,
                                             int M, int N, int K) {
    __shared__ float At[32][68];
    __shared__ float Wt[32][68];
    const int m0 = blockIdx.x * 64, n0 = blockIdx.y * 64;
    const int t = threadIdx.x;
    const int tx = t & 7, ty = t >> 3;
    float acc[8][8] = {};
    for (int kc = 0; kc < K; kc += 32) {
        #pragma unroll
        for (int i = 0; i < 8; ++i) {
            int e = t + i * 64;
            int row = e >> 3, c4 = (e & 7) * 4;
            float4 v = *(const float4*)&A[(size_t)(m0 + row) * K + kc + c4];
            At[c4 + 0][row] = v.x; At[c4 + 1][row] = v.y; At[c4 + 2][row] = v.z; At[c4 + 3][row] = v.w;
            int n = n0 + row;
            float4 wv = make_float4(0.f, 0.f, 0.f, 0.f);
            if (n < N) wv = *(const float4*)&W[(size_t)n * K + kc + c4];
            Wt[c4 + 0][row] = wv.x; Wt[c4 + 1][row] = wv.y; Wt[c4 + 2][row] = wv.z; Wt[c4 + 3][row] = wv.w;
        }
        __syncthreads();
        #pragma unroll
        for (int kk = 0; kk < 32; ++kk) {
            float4 a0 = *(const float4*)&At[kk][ty * 8];
            float4 a1 = *(const float4*)&At[kk][ty * 8 + 4];
            float4 b0 = *(const float4*)&Wt[kk][tx * 8];
            float4 b1 = *(const float4*)&Wt[kk][tx * 8 + 4];
            float a[8] = {a0.x, a0.y, a0.z, a0.w, a1.x, a1.y, a1.z, a1.w};
            float b[8] = {b0.x, b0.y, b0.z, b0.w, b1.x, b1.y, b1.z, b1.w};
            #pragma unroll
            for (int i = 0; i < 8; ++i)
                #pragma unroll
                for (int j = 0; j < 8; ++j) acc[i][j] += a[i] * b[j];
        }
        __syncthreads();
    }
    #pragma unroll
    for (int i = 0; i < 8; ++i) {
        int m = m0 + ty * 8 + i;
        #pragma unroll
        for (int j = 0; j < 8; ++j) {
            int n = n0 + tx * 8 + j;
            if (n < N) {
                float v = acc[i][j] + bias[n];
                if (RELU) v = fmaxf(v, 0.0f);
                C[(size_t)m * N + n] = v;
            }
        }
    }
}

// ---------------- embedding ----------------
__global__ void embed_kernel(const int* __restrict__ lang, const float* __restrict__ emb,
                             float* __restrict__ out) {
    int g = blockIdx.x * 256 + threadIdx.x;
    if (g < TBTOT * 32) { int r = g >> 5, c = g & 31; out[g] = emb[lang[r] * 32 + c]; }
}

// ---------------- concat [img_hidden(256) | lang_hidden(32)] ----------------
__global__ void concat_kernel(const float* __restrict__ img_h, const float* __restrict__ lang_h,
                              float* __restrict__ out) {
    int r = blockIdx.x, c = threadIdx.x;
    out[r * 288 + c] = (c < 256) ? img_h[r * 256 + c] : lang_h[r * 32 + (c - 256)];
}

// ---------------- persistent MFMA LSTM scan (split-bf16, 3-pass) ----------------
// grid (H/16 j-tiles, 4 b-tiles), 256 threads = 4 waves; wave q computes gate q for
// a 32(batch) x 16(j) tile. h staged hi/lo in LDS per 256-k chunk with the XOR slot
// layout slot = seg*32 + ((row^seg)&31)  (conflict-free ds_write_b128 AND ds_read_b128).
// Whh fragments pre-ordered so each B-load is one coalesced 1KB global_load_dwordx4.
template <int H, bool PER_ENV>
__global__ __launch_bounds__(256) void lstm_mfma_kernel(
        const float* __restrict__ xw,      // [T*B][4H]  (x@Wih^T + bih + bhh)
        const short* __restrict__ wf_hi,   // fragment-ordered Whh hi
        const short* __restrict__ wf_lo,
        const float* __restrict__ done,
        const float* __restrict__ h0, const float* __restrict__ c0,
        short* __restrict__ hbuf_hi,       // [2][B][H]
        short* __restrict__ hbuf_lo,
        float* __restrict__ hs,            // [T*B][H]
        unsigned* __restrict__ bar_cnt, unsigned nblk) {
    __shared__ bf16x8 lsA[2][1024];        // hi/lo staged h chunk: [32 rows][256 k]
    __shared__ float  gbuf[4][32][16];
    const int t    = threadIdx.x;
    const int lane = t & 63;
    const int q    = t >> 6;               // wave index = gate
    const int jt   = blockIdx.x;
    const int j0   = jt * 16;
    const int b0   = blockIdx.y * 32;
    const int jl   = t & 15, bl = t >> 4 & 15;
    const int jg   = j0 + jl;
    const int njt  = H >> 4, nks = H >> 5;

    float c_reg[2];
    c_reg[0] = c0[(b0 + bl) * H + jg];
    c_reg[1] = c0[(b0 + bl + 16) * H + jg];
    {   // init split h0 for this block's cells
        #pragma unroll
        for (int e = 0; e < 2; ++e) {
            int b = b0 + bl + e * 16;
            float v = h0[(size_t)b * H + jg];
            short a = f32_to_bf16_rne(v);
            short l = f32_to_bf16_rne(v - bf16s_to_f32(a));
            hbuf_hi[(size_t)b * H + jg] = a;
            hbuf_lo[(size_t)b * H + jg] = l;
        }
    }
    unsigned bar = 1;
    gridbar(bar_cnt, nblk * bar); ++bar;

    const bf16x8 zero8 = {0, 0, 0, 0, 0, 0, 0, 0};
    int cur = 0;
    for (int st = 0; st < T_STEPS; ++st) {
        f32x4 acc0 = {0.f, 0.f, 0.f, 0.f};
        f32x4 acc1 = {0.f, 0.f, 0.f, 0.f};
        const short* hsh = hbuf_hi + (size_t)cur * (BATCH * H);
        const short* hsl = hbuf_lo + (size_t)cur * (BATCH * H);
        const bf16x8* bfh = (const bf16x8*)wf_hi + (size_t)(q * njt + jt) * nks * 64;
        const bf16x8* bfl = (const bf16x8*)wf_lo + (size_t)(q * njt + jt) * nks * 64;
        float m_step = PER_ENV ? 0.0f : (1.0f - done[st]);

        for (int cch = 0; cch < H / 256; ++cch) {
            const int k0 = cch * 256;
            #pragma unroll
            for (int i = 0; i < 4; ++i) {
                int idx = i * 256 + t;
                int row = idx >> 5, seg = idx & 31;
                float m = PER_ENV ? (1.0f - done[st * BATCH + b0 + row]) : m_step;
                int slot = seg * 32 + ((row ^ seg) & 31);
                bf16x8 vh = *(const bf16x8*)&hsh[(size_t)(b0 + row) * H + k0 + seg * 8];
                bf16x8 vl = *(const bf16x8*)&hsl[(size_t)(b0 + row) * H + k0 + seg * 8];
                if (m == 0.0f) { vh = zero8; vl = zero8; }
                lsA[0][slot] = vh;
                lsA[1][slot] = vl;
            }
            __syncthreads();
            #pragma unroll
            for (int ksl = 0; ksl < 8; ++ksl) {
                int ks = (k0 >> 5) + ksl;
                bf16x8 b_hi = bfh[(size_t)ks * 64 + lane];
                bf16x8 b_lo = bfl[(size_t)ks * 64 + lane];
                int kgrp = ksl * 4 + (lane >> 4);
                int r0 = lane & 15, r1 = r0 + 16;
                bf16x8 a0h = lsA[0][kgrp * 32 + ((r0 ^ kgrp) & 31)];
                bf16x8 a0l = lsA[1][kgrp * 32 + ((r0 ^ kgrp) & 31)];
                bf16x8 a1h = lsA[0][kgrp * 32 + ((r1 ^ kgrp) & 31)];
                bf16x8 a1l = lsA[1][kgrp * 32 + ((r1 ^ kgrp) & 31)];
                acc0 = __builtin_amdgcn_mfma_f32_16x16x32_bf16(a0h, b_hi, acc0, 0, 0, 0);
                acc1 = __builtin_amdgcn_mfma_f32_16x16x32_bf16(a1h, b_hi, acc1, 0, 0, 0);
                acc0 = __builtin_amdgcn_mfma_f32_16x16x32_bf16(a0h, b_lo, acc0, 0, 0, 0);
                acc1 = __builtin_amdgcn_mfma_f32_16x16x32_bf16(a1h, b_lo, acc1, 0, 0, 0);
                acc0 = __builtin_amdgcn_mfma_f32_16x16x32_bf16(a0l, b_hi, acc0, 0, 0, 0);
                acc1 = __builtin_amdgcn_mfma_f32_16x16x32_bf16(a1l, b_hi, acc1, 0, 0, 0);
            }
            __syncthreads();
        }

        // cross-wave gate exchange: C/D layout col=lane&15, row=(lane>>4)*4+r
        #pragma unroll
        for (int r = 0; r < 4; ++r) {
            gbuf[q][(lane >> 4) * 4 + r][lane & 15]      = acc0[r];
            gbuf[q][16 + (lane >> 4) * 4 + r][lane & 15] = acc1[r];
        }
        __syncthreads();

        #pragma unroll
        for (int e = 0; e < 2; ++e) {
            int b_loc = bl + e * 16;
            int bgl = b0 + b_loc;
            float m = PER_ENV ? (1.0f - done[st * BATCH + bgl]) : m_step;
            const float* xr = xw + (size_t)(st * BATCH + bgl) * (4 * H);
            float gi = gbuf[0][b_loc][jl] + xr[jg];
            float gf = gbuf[1][b_loc][jl] + xr[H + jg];
            float gg = gbuf[2][b_loc][jl] + xr[2 * H + jg];
            float go = gbuf[3][b_loc][jl] + xr[3 * H + jg];
            float cc = fast_sigm(gf) * (c_reg[e] * m) + fast_sigm(gi) * fast_tanh(gg);
            float hh = fast_sigm(go) * fast_tanh(cc);
            c_reg[e] = cc;
            hs[(size_t)(st * BATCH + bgl) * H + jg] = hh;
            short hhi = f32_to_bf16_rne(hh);
            short hlo = f32_to_bf16_rne(hh - bf16s_to_f32(hhi));
            size_t ho = (size_t)(cur ^ 1) * (BATCH * H) + (size_t)bgl * H + jg;
            hbuf_hi[ho] = hhi;
            hbuf_lo[ho] = hlo;
        }
        gridbar(bar_cnt, nblk * bar); ++bar;
        cur ^= 1;
    }
}

extern "C" void kernel_launch(void* const* d_in, const int* in_sizes, int n_in,
                              void* d_out, int out_size, void* d_ws, size_t ws_size,
                              hipStream_t stream) {
    const float* x_img    = (const float*)d_in[0];
    const int*   x_lang   = (const int*)d_in[1];
    const float* done     = (const float*)d_in[2];
    const float* enc_h0   = (const float*)d_in[3];
    const float* enc_c0   = (const float*)d_in[4];
    const float* mem_h0   = (const float*)d_in[5];
    const float* mem_c0   = (const float*)d_in[6];
    const float* emb      = (const float*)d_in[7];
    const float* conv1_w  = (const float*)d_in[8];
    const float* conv1_b  = (const float*)d_in[9];
    const float* conv2_w  = (const float*)d_in[10];
    const float* conv2_b  = (const float*)d_in[11];
    const float* conv3_w  = (const float*)d_in[12];
    const float* conv3_b  = (const float*)d_in[13];
    const float* fc_w     = (const float*)d_in[14];
    const float* fc_b     = (const float*)d_in[15];
    const float* enc_Wih  = (const float*)d_in[16];
    const float* enc_Whh  = (const float*)d_in[17];
    const float* enc_bih  = (const float*)d_in[18];
    const float* enc_bhh  = (const float*)d_in[19];
    const float* lemb_w   = (const float*)d_in[20];
    const float* lemb_b   = (const float*)d_in[21];
    const float* mem_Wih  = (const float*)d_in[22];
    const float* mem_Whh  = (const float*)d_in[23];
    const float* mem_bih  = (const float*)d_in[24];
    const float* mem_bhh  = (const float*)d_in[25];
    const float* actor_w  = (const float*)d_in[26];
    const float* actor_b  = (const float*)d_in[27];
    const float* critic_w = (const float*)d_in[28];
    const float* critic_b = (const float*)d_in[29];

    float* ws = (float*)d_ws;
    float* conv3_flat = ws + OFF_CONV3;
    short* mem_wf_hi  = (short*)(ws + OFF_MWFHI);
    short* mem_wf_lo  = (short*)(ws + OFF_MWFLO);
    short* enc_wf_hi  = (short*)(ws + OFF_EWFHI);
    short* enc_wf_lo  = (short*)(ws + OFF_EWFLO);
    short* hbm_hi     = (short*)(ws + OFF_HBMHI);
    short* hbm_lo     = (short*)(ws + OFF_HBMLO);
    short* hbe_hi     = (short*)(ws + OFF_HBEHI);
    short* hbe_lo     = (short*)(ws + OFF_HBELO);
    float* img_hidden = ws + OFF_IMGH;
    float* lang_in    = ws + OFF_LANGIN;
    float* enc_xW     = ws + OFF_ENCXW;
    float* enc_hs     = ws + OFF_ENCHS;
    float* lang_h     = ws + OFF_LANGH;
    float* hidden     = ws + OFF_HIDDEN;
    float* mem_xW     = ws + OFF_MEMXW;
    float* mem_hs     = ws + OFF_MEMHS;
    float* enc_bc     = ws + OFF_ENCBC;
    float* mem_bc     = ws + OFF_MEMBC;
    float* head_w     = ws + OFF_HEADW;
    float* head_b     = ws + OFF_HEADB;
    unsigned* bars    = (unsigned*)(ws + OFF_BARS);

    prep_kernel<<<64, 256, 0, stream>>>(enc_bih, enc_bhh, mem_bih, mem_bhh,
                                        actor_w, actor_b, critic_w, critic_b,
                                        enc_bc, mem_bc, head_w, head_b, bars);
    conv_kernel<<<TBTOT, 256, 0, stream>>>(x_img, conv1_w, conv1_b, conv2_w, conv2_b,
                                           conv3_w, conv3_b, conv3_flat);
    gemm64<true><<<dim3(128, 4), 64, 0, stream>>>(conv3_flat, fc_w, fc_b, img_hidden, TBTOT, 256, 1568);
    // conv3 region dead from here; build LSTM split-weight fragments in it
    split_frag_kernel<<<65536, 256, 0, stream>>>(mem_Whh, mem_wf_hi, mem_wf_lo, 1024);
    split_frag_kernel<<<4096, 256, 0, stream>>>(enc_Whh, enc_wf_hi, enc_wf_lo, 256);
    embed_kernel<<<1024, 256, 0, stream>>>(x_lang, emb, lang_in);
    gemm64<false><<<dim3(128, 16), 64, 0, stream>>>(lang_in, enc_Wih, enc_bc, enc_xW, TBTOT, 1024, 32);
    lstm_mfma_kernel<256, false><<<dim3(16, 4), 256, 0, stream>>>(
        enc_xW, enc_wf_hi, enc_wf_lo, done, enc_h0, enc_c0, hbe_hi, hbe_lo, enc_hs, bars + 0, 64u);
    gemm64<true><<<dim3(128, 1), 64, 0, stream>>>(enc_hs, lemb_w, lemb_b, lang_h, TBTOT, 32, 256);
    concat_kernel<<<TBTOT, 288, 0, stream>>>(img_hidden, lang_h, hidden);
    gemm64<false><<<dim3(128, 64), 64, 0, stream>>>(hidden, mem_Wih, mem_bc, mem_xW, TBTOT, 4096, 288);
    lstm_mfma_kernel<1024, true><<<dim3(64, 4), 256, 0, stream>>>(
        mem_xW, mem_wf_hi, mem_wf_lo, done, mem_h0, mem_c0, hbm_hi, hbm_lo, mem_hs, bars + 8, 256u);
    gemm64<false><<<dim3(128, 1), 64, 0, stream>>>(mem_hs, head_w, head_b, (float*)d_out, TBTOT, 16, 1024);
}

// Round 3
// 3993.694 us; speedup vs baseline: 1.7905x; 1.1355x over previous
//
#include <hip/hip_runtime.h>
#include <math.h>

#define T_STEPS 64
#define BATCH   128
#define TBTOT   8192

typedef __attribute__((ext_vector_type(8))) short bf16x8;
typedef __attribute__((ext_vector_type(4))) float f32x4;

// ---------------- workspace layout (float offsets) ----------------
static const size_t OFF_CONV3  = 0;              // [8192][1568] f32 (phase 1)
static const size_t OFF_MWFHI  = 0;              // [4096*1024] bf16  (phase 2)
static const size_t OFF_MWFLO  = 2097152;        // [4096*1024] bf16
static const size_t OFF_EWFHI  = 4194304;        // [1024*256] bf16
static const size_t OFF_EWFLO  = 4325376;        // [1024*256] bf16
static const size_t OFF_HBMHI  = 4456448;        // [2][128][1024] bf16
static const size_t OFF_HBMLO  = 4587520;        // [2][128][1024] bf16
static const size_t OFF_HBEHI  = 4718592;        // [2][128][256] bf16
static const size_t OFF_HBELO  = 4734976;        // [2][128][256] bf16
static const size_t OFF_IMGH   = 12845056;       // [8192][256]
static const size_t OFF_LANGIN = 14942208;       // [8192][32]
static const size_t OFF_ENCXW  = 15204352;       // [8192][1024]
static const size_t OFF_ENCHS  = 23592960;       // [8192][256]
static const size_t OFF_LANGH  = 25690112;       // [8192][32]
static const size_t OFF_HIDDEN = 25952256;       // [8192][288]
static const size_t OFF_MEMXW  = 28311552;       // [8192][4096]
static const size_t OFF_MEMHS  = 61865984;       // [8192][1024]
static const size_t OFF_ENCBC  = 70582272;       // [1024]
static const size_t OFF_MEMBC  = 70583296;       // [4096]
static const size_t OFF_HEADW  = 70587392;       // [16][1024]
static const size_t OFF_HEADB  = 70603776;       // [16]
static const size_t OFF_BARS   = 70603792;       // 512 uints (padded barrier counters)

__device__ __forceinline__ float fast_sigm(float x) { return 1.0f / (1.0f + __expf(-x)); }
__device__ __forceinline__ float fast_tanh(float x) { return 2.0f / (1.0f + __expf(-2.0f * x)) - 1.0f; }

__device__ __forceinline__ short f32_to_bf16_rne(float x) {
    unsigned u = __float_as_uint(x);
    unsigned r = (u + 0x7fffu + ((u >> 16) & 1u)) >> 16;
    return (short)r;
}
__device__ __forceinline__ float bf16s_to_f32(short s) {
    return __uint_as_float(((unsigned)(unsigned short)s) << 16);
}

// -------- hierarchical device-scope grid barrier --------
// cnts layout (uints): group g arrive counter at cnts[g*16] (g=0..7, own 64B line),
// global phase counter at cnts[128]. All monotone; prep zeroes them each launch.
// round = 1,2,3...; grp_target = blocks per group.
__device__ __forceinline__ void gridbar2(unsigned* cnts, unsigned round,
                                         unsigned grp, unsigned grp_target) {
    __syncthreads();
    if (threadIdx.x == 0) {
        __threadfence();  // release prior global writes
        unsigned old = __hip_atomic_fetch_add(&cnts[grp * 16], 1u,
                                              __ATOMIC_RELEASE, __HIP_MEMORY_SCOPE_AGENT);
        if (old + 1u == grp_target * round) {
            __hip_atomic_fetch_add(&cnts[128], 1u,
                                   __ATOMIC_RELEASE, __HIP_MEMORY_SCOPE_AGENT);
        }
        while (__hip_atomic_load(&cnts[128], __ATOMIC_ACQUIRE,
                                 __HIP_MEMORY_SCOPE_AGENT) < 8u * round) {
            __builtin_amdgcn_s_sleep(2);
        }
    }
    __syncthreads();
}

// ---------------- prep: combined biases, head weights, zero barriers ----------------
__global__ void prep_kernel(const float* __restrict__ enc_bih, const float* __restrict__ enc_bhh,
                            const float* __restrict__ mem_bih, const float* __restrict__ mem_bhh,
                            const float* __restrict__ actor_w, const float* __restrict__ actor_b,
                            const float* __restrict__ critic_w, const float* __restrict__ critic_b,
                            float* __restrict__ enc_bc, float* __restrict__ mem_bc,
                            float* __restrict__ head_w, float* __restrict__ head_b,
                            unsigned* __restrict__ bars) {
    int g = blockIdx.x * 256 + threadIdx.x;
    if (g < 1024)  enc_bc[g] = enc_bih[g] + enc_bhh[g];
    if (g < 4096)  mem_bc[g] = mem_bih[g] + mem_bhh[g];
    if (g < 16384) { int j = g >> 10, k = g & 1023; head_w[g] = (j < 15) ? actor_w[j * 1024 + k] : critic_w[k]; }
    if (g < 16)    head_b[g] = (g < 15) ? actor_b[g] : critic_b[0];
    if (g < 512)   bars[g] = 0u;
}

// ---------------- split Whh into MFMA-fragment-ordered bf16 hi/lo ----------------
__global__ void split_frag_kernel(const float* __restrict__ W, short* __restrict__ hi,
                                  short* __restrict__ lo, int H) {
    size_t f = (size_t)blockIdx.x * 256 + threadIdx.x;
    size_t total = (size_t)4 * H * H;
    if (f >= total) return;
    int e    = (int)(f & 7);
    int lane = (int)((f >> 3) & 63);
    size_t rest = f >> 9;
    int nks = H >> 5;
    int ks  = (int)(rest % nks);
    int qjt = (int)(rest / nks);
    int njt = H >> 4;
    int qq = qjt / njt, jt = qjt - qq * njt;
    int n = qq * H + jt * 16 + (lane & 15);
    int k = ks * 32 + (lane >> 4) * 8 + e;
    float w = W[(size_t)n * H + k];
    short a = f32_to_bf16_rne(w);
    short b = f32_to_bf16_rne(w - bf16s_to_f32(a));
    hi[f] = a; lo[f] = b;
}

// ---------------- fused conv stack, one block per image ----------------
__global__ __launch_bounds__(256) void conv_kernel(const float* __restrict__ x,
        const float* __restrict__ w1, const float* __restrict__ b1,
        const float* __restrict__ w2, const float* __restrict__ b2,
        const float* __restrict__ w3, const float* __restrict__ b3,
        float* __restrict__ out) {
    __shared__ float arena[16384];
    const int t = threadIdx.x;
    const size_t img = blockIdx.x;

    float* s_out1 = arena;
    float* s_w1   = arena + 1936;
    float* s_b1   = arena + 3232;
    float* s_img  = arena + 3248;
    const float* xi = x + img * 9801;
    for (int i = t; i < 9801; i += 256) s_img[i] = xi[i] * (1.0f / 255.0f);
    for (int i = t; i < 1296; i += 256) s_w1[i] = w1[i];
    if (t < 16) s_b1[t] = b1[t];
    __syncthreads();

    if (t < 176) {
        int c = t / 11, i = t - c * 11;
        float accr[11];
        #pragma unroll
        for (int j = 0; j < 11; ++j) accr[j] = s_b1[c];
        for (int ky = 0; ky < 9; ++ky) {
            const float* irow = s_img + (i * 9 + ky) * 99;
            const float* wrow = s_w1 + c * 81 + ky * 9;
            for (int kx = 0; kx < 9; ++kx) {
                float wv = wrow[kx];
                #pragma unroll
                for (int j = 0; j < 11; ++j) accr[j] += wv * irow[j * 9 + kx];
            }
        }
        #pragma unroll
        for (int j = 0; j < 11; ++j) s_out1[c * 121 + i * 11 + j] = fmaxf(accr[j], 0.0f);
    }
    __syncthreads();

    float* s_w2   = arena + 1936;
    float* s_b2   = arena + 6544;
    float* s_out2 = arena + 13792;
    for (int i = t; i < 4608; i += 256) s_w2[i] = w2[i];
    if (t < 32) s_b2[t] = b2[t];
    __syncthreads();

    for (int rr = 0; rr < 2; ++rr) {
        int task = rr * 256 + t;
        if (task < 288) {
            int c = task / 9, i = task - c * 9;
            float accr[9];
            #pragma unroll
            for (int j = 0; j < 9; ++j) accr[j] = s_b2[c];
            for (int ic = 0; ic < 16; ++ic) {
                const float* ibase = s_out1 + ic * 121 + i * 11;
                const float* wbase = s_w2 + (c * 16 + ic) * 9;
                #pragma unroll
                for (int ky = 0; ky < 3; ++ky) {
                    const float* irow = ibase + ky * 11;
                    #pragma unroll
                    for (int kx = 0; kx < 3; ++kx) {
                        float wv = wbase[ky * 3 + kx];
                        #pragma unroll
                        for (int j = 0; j < 9; ++j) accr[j] += wv * irow[j + kx];
                    }
                }
            }
            #pragma unroll
            for (int j = 0; j < 9; ++j) s_out2[c * 81 + i * 9 + j] = fmaxf(accr[j], 0.0f);
        }
    }
    __syncthreads();

    float* s_w3   = arena;
    float* s_b3   = arena + 9216;
    float* s_out3 = arena + 9248;
    for (int i = t; i < 9216; i += 256) s_w3[i] = w3[i];
    if (t < 32) s_b3[t] = b3[t];
    __syncthreads();

    if (t < 224) {
        int c = t / 7, i = t - c * 7;
        float accr[7];
        #pragma unroll
        for (int j = 0; j < 7; ++j) accr[j] = s_b3[c];
        for (int ic = 0; ic < 32; ++ic) {
            const float* ibase = s_out2 + ic * 81 + i * 9;
            const float* wbase = s_w3 + (c * 32 + ic) * 9;
            #pragma unroll
            for (int ky = 0; ky < 3; ++ky) {
                const float* irow = ibase + ky * 9;
                #pragma unroll
                for (int kx = 0; kx < 3; ++kx) {
                    float wv = wbase[ky * 3 + kx];
                    #pragma unroll
                    for (int j = 0; j < 7; ++j) accr[j] += wv * irow[j + kx];
                }
            }
        }
        #pragma unroll
        for (int j = 0; j < 7; ++j) s_out3[c * 49 + i * 7 + j] = fmaxf(accr[j], 0.0f);
    }
    __syncthreads();
    float* og = out + img * 1568;
    for (int i = t; i < 1568; i += 256) og[i] = s_out3[i];
}

// ---------------- generic tiled GEMM: C[M,N] = act(A[M,K] @ W[N,K]^T + bias) ----------------
template <bool RELU>
__global__ __launch_bounds__(64) void gemm64(const float* __restrict__ A, const float* __restrict__ W,
                                             const float* __restrict__ bias, float* __restrict__ C,
                                             int M, int N, int K) {
    __shared__ float At[32][68];
    __shared__ float Wt[32][68];
    const int m0 = blockIdx.x * 64, n0 = blockIdx.y * 64;
    const int t = threadIdx.x;
    const int tx = t & 7, ty = t >> 3;
    float acc[8][8] = {};
    for (int kc = 0; kc < K; kc += 32) {
        #pragma unroll
        for (int i = 0; i < 8; ++i) {
            int e = t + i * 64;
            int row = e >> 3, c4 = (e & 7) * 4;
            float4 v = *(const float4*)&A[(size_t)(m0 + row) * K + kc + c4];
            At[c4 + 0][row] = v.x; At[c4 + 1][row] = v.y; At[c4 + 2][row] = v.z; At[c4 + 3][row] = v.w;
            int n = n0 + row;
            float4 wv = make_float4(0.f, 0.f, 0.f, 0.f);
            if (n < N) wv = *(const float4*)&W[(size_t)n * K + kc + c4];
            Wt[c4 + 0][row] = wv.x; Wt[c4 + 1][row] = wv.y; Wt[c4 + 2][row] = wv.z; Wt[c4 + 3][row] = wv.w;
        }
        __syncthreads();
        #pragma unroll
        for (int kk = 0; kk < 32; ++kk) {
            float4 a0 = *(const float4*)&At[kk][ty * 8];
            float4 a1 = *(const float4*)&At[kk][ty * 8 + 4];
            float4 b0 = *(const float4*)&Wt[kk][tx * 8];
            float4 b1 = *(const float4*)&Wt[kk][tx * 8 + 4];
            float a[8] = {a0.x, a0.y, a0.z, a0.w, a1.x, a1.y, a1.z, a1.w};
            float b[8] = {b0.x, b0.y, b0.z, b0.w, b1.x, b1.y, b1.z, b1.w};
            #pragma unroll
            for (int i = 0; i < 8; ++i)
                #pragma unroll
                for (int j = 0; j < 8; ++j) acc[i][j] += a[i] * b[j];
        }
        __syncthreads();
    }
    #pragma unroll
    for (int i = 0; i < 8; ++i) {
        int m = m0 + ty * 8 + i;
        #pragma unroll
        for (int j = 0; j < 8; ++j) {
            int n = n0 + tx * 8 + j;
            if (n < N) {
                float v = acc[i][j] + bias[n];
                if (RELU) v = fmaxf(v, 0.0f);
                C[(size_t)m * N + n] = v;
            }
        }
    }
}

// ---------------- embedding ----------------
__global__ void embed_kernel(const int* __restrict__ lang, const float* __restrict__ emb,
                             float* __restrict__ out) {
    int g = blockIdx.x * 256 + threadIdx.x;
    if (g < TBTOT * 32) { int r = g >> 5, c = g & 31; out[g] = emb[lang[r] * 32 + c]; }
}

// ---------------- concat [img_hidden(256) | lang_hidden(32)] ----------------
__global__ void concat_kernel(const float* __restrict__ img_h, const float* __restrict__ lang_h,
                              float* __restrict__ out) {
    int r = blockIdx.x, c = threadIdx.x;
    out[r * 288 + c] = (c < 256) ? img_h[r * 256 + c] : lang_h[r * 32 + (c - 256)];
}

// ---------------- persistent MFMA LSTM scan (split-bf16, 3-pass) ----------------
template <int H, bool PER_ENV>
__global__ __launch_bounds__(256) void lstm_mfma_kernel(
        const float* __restrict__ xw,      // [T*B][4H]
        const short* __restrict__ wf_hi,   // fragment-ordered Whh hi
        const short* __restrict__ wf_lo,
        const float* __restrict__ done,
        const float* __restrict__ h0, const float* __restrict__ c0,
        short* __restrict__ hbuf_hi,       // [2][B][H]
        short* __restrict__ hbuf_lo,
        float* __restrict__ hs,            // [T*B][H]
        unsigned* __restrict__ bar_cnt, unsigned grp_target) {
    __shared__ bf16x8 lsA[2][1024];
    __shared__ float  gbuf[4][32][16];
    const int t    = threadIdx.x;
    const int lane = t & 63;
    const int q    = t >> 6;
    const int jt   = blockIdx.x;
    const int j0   = jt * 16;
    const int b0   = blockIdx.y * 32;
    const int jl   = t & 15, bl = t >> 4 & 15;
    const int jg   = j0 + jl;
    const int njt  = H >> 4, nks = H >> 5;
    const unsigned grp = (blockIdx.x + blockIdx.y * gridDim.x) & 7u;

    float c_reg[2];
    c_reg[0] = c0[(b0 + bl) * H + jg];
    c_reg[1] = c0[(b0 + bl + 16) * H + jg];
    {
        #pragma unroll
        for (int e = 0; e < 2; ++e) {
            int b = b0 + bl + e * 16;
            float v = h0[(size_t)b * H + jg];
            short a = f32_to_bf16_rne(v);
            short l = f32_to_bf16_rne(v - bf16s_to_f32(a));
            hbuf_hi[(size_t)b * H + jg] = a;
            hbuf_lo[(size_t)b * H + jg] = l;
        }
    }
    unsigned bar = 1;
    gridbar2(bar_cnt, bar, grp, grp_target); ++bar;

    const bf16x8 zero8 = {0, 0, 0, 0, 0, 0, 0, 0};
    int cur = 0;
    for (int st = 0; st < T_STEPS; ++st) {
        // ---- prefetch xw gate values for this thread's cells (independent of h) ----
        float m_step = PER_ENV ? 0.0f : (1.0f - done[st]);
        float xg[2][4];
        float m_e[2];
        #pragma unroll
        for (int e = 0; e < 2; ++e) {
            int bgl = b0 + bl + e * 16;
            const float* xr = xw + (size_t)(st * BATCH + bgl) * (4 * H);
            #pragma unroll
            for (int g4 = 0; g4 < 4; ++g4) xg[e][g4] = xr[g4 * H + jg];
            m_e[e] = PER_ENV ? (1.0f - done[st * BATCH + bgl]) : m_step;
        }

        f32x4 acc0 = {0.f, 0.f, 0.f, 0.f};
        f32x4 acc1 = {0.f, 0.f, 0.f, 0.f};
        const short* hsh = hbuf_hi + (size_t)cur * (BATCH * H);
        const short* hsl = hbuf_lo + (size_t)cur * (BATCH * H);
        const bf16x8* bfh = (const bf16x8*)wf_hi + (size_t)(q * njt + jt) * nks * 64;
        const bf16x8* bfl = (const bf16x8*)wf_lo + (size_t)(q * njt + jt) * nks * 64;

        for (int cch = 0; cch < H / 256; ++cch) {
            const int k0 = cch * 256;
            #pragma unroll
            for (int i = 0; i < 4; ++i) {
                int idx = i * 256 + t;
                int row = idx >> 5, seg = idx & 31;
                float m = PER_ENV ? (1.0f - done[st * BATCH + b0 + row]) : m_step;
                int slot = seg * 32 + ((row ^ seg) & 31);
                bf16x8 vh = *(const bf16x8*)&hsh[(size_t)(b0 + row) * H + k0 + seg * 8];
                bf16x8 vl = *(const bf16x8*)&hsl[(size_t)(b0 + row) * H + k0 + seg * 8];
                if (m == 0.0f) { vh = zero8; vl = zero8; }
                lsA[0][slot] = vh;
                lsA[1][slot] = vl;
            }
            __syncthreads();
            #pragma unroll
            for (int ksl = 0; ksl < 8; ++ksl) {
                int ks = (k0 >> 5) + ksl;
                bf16x8 b_hi = bfh[(size_t)ks * 64 + lane];
                bf16x8 b_lo = bfl[(size_t)ks * 64 + lane];
                int kgrp = ksl * 4 + (lane >> 4);
                int r0 = lane & 15, r1 = r0 + 16;
                bf16x8 a0h = lsA[0][kgrp * 32 + ((r0 ^ kgrp) & 31)];
                bf16x8 a0l = lsA[1][kgrp * 32 + ((r0 ^ kgrp) & 31)];
                bf16x8 a1h = lsA[0][kgrp * 32 + ((r1 ^ kgrp) & 31)];
                bf16x8 a1l = lsA[1][kgrp * 32 + ((r1 ^ kgrp) & 31)];
                acc0 = __builtin_amdgcn_mfma_f32_16x16x32_bf16(a0h, b_hi, acc0, 0, 0, 0);
                acc1 = __builtin_amdgcn_mfma_f32_16x16x32_bf16(a1h, b_hi, acc1, 0, 0, 0);
                acc0 = __builtin_amdgcn_mfma_f32_16x16x32_bf16(a0h, b_lo, acc0, 0, 0, 0);
                acc1 = __builtin_amdgcn_mfma_f32_16x16x32_bf16(a1h, b_lo, acc1, 0, 0, 0);
                acc0 = __builtin_amdgcn_mfma_f32_16x16x32_bf16(a0l, b_hi, acc0, 0, 0, 0);
                acc1 = __builtin_amdgcn_mfma_f32_16x16x32_bf16(a1l, b_hi, acc1, 0, 0, 0);
            }
            __syncthreads();
        }

        #pragma unroll
        for (int r = 0; r < 4; ++r) {
            gbuf[q][(lane >> 4) * 4 + r][lane & 15]      = acc0[r];
            gbuf[q][16 + (lane >> 4) * 4 + r][lane & 15] = acc1[r];
        }
        __syncthreads();

        #pragma unroll
        for (int e = 0; e < 2; ++e) {
            int b_loc = bl + e * 16;
            int bgl = b0 + b_loc;
            float m = m_e[e];
            float gi = gbuf[0][b_loc][jl] + xg[e][0];
            float gf = gbuf[1][b_loc][jl] + xg[e][1];
            float gg = gbuf[2][b_loc][jl] + xg[e][2];
            float go = gbuf[3][b_loc][jl] + xg[e][3];
            float cc = fast_sigm(gf) * (c_reg[e] * m) + fast_sigm(gi) * fast_tanh(gg);
            float hh = fast_sigm(go) * fast_tanh(cc);
            c_reg[e] = cc;
            hs[(size_t)(st * BATCH + bgl) * H + jg] = hh;
            short hhi = f32_to_bf16_rne(hh);
            short hlo = f32_to_bf16_rne(hh - bf16s_to_f32(hhi));
            size_t ho = (size_t)(cur ^ 1) * (BATCH * H) + (size_t)bgl * H + jg;
            hbuf_hi[ho] = hhi;
            hbuf_lo[ho] = hlo;
        }
        gridbar2(bar_cnt, bar, grp, grp_target); ++bar;
        cur ^= 1;
    }
}

extern "C" void kernel_launch(void* const* d_in, const int* in_sizes, int n_in,
                              void* d_out, int out_size, void* d_ws, size_t ws_size,
                              hipStream_t stream) {
    const float* x_img    = (const float*)d_in[0];
    const int*   x_lang   = (const int*)d_in[1];
    const float* done     = (const float*)d_in[2];
    const float* enc_h0   = (const float*)d_in[3];
    const float* enc_c0   = (const float*)d_in[4];
    const float* mem_h0   = (const float*)d_in[5];
    const float* mem_c0   = (const float*)d_in[6];
    const float* emb      = (const float*)d_in[7];
    const float* conv1_w  = (const float*)d_in[8];
    const float* conv1_b  = (const float*)d_in[9];
    const float* conv2_w  = (const float*)d_in[10];
    const float* conv2_b  = (const float*)d_in[11];
    const float* conv3_w  = (const float*)d_in[12];
    const float* conv3_b  = (const float*)d_in[13];
    const float* fc_w     = (const float*)d_in[14];
    const float* fc_b     = (const float*)d_in[15];
    const float* enc_Wih  = (const float*)d_in[16];
    const float* enc_Whh  = (const float*)d_in[17];
    const float* enc_bih  = (const float*)d_in[18];
    const float* enc_bhh  = (const float*)d_in[19];
    const float* lemb_w   = (const float*)d_in[20];
    const float* lemb_b   = (const float*)d_in[21];
    const float* mem_Wih  = (const float*)d_in[22];
    const float* mem_Whh  = (const float*)d_in[23];
    const float* mem_bih  = (const float*)d_in[24];
    const float* mem_bhh  = (const float*)d_in[25];
    const float* actor_w  = (const float*)d_in[26];
    const float* actor_b  = (const float*)d_in[27];
    const float* critic_w = (const float*)d_in[28];
    const float* critic_b = (const float*)d_in[29];

    float* ws = (float*)d_ws;
    float* conv3_flat = ws + OFF_CONV3;
    short* mem_wf_hi  = (short*)(ws + OFF_MWFHI);
    short* mem_wf_lo  = (short*)(ws + OFF_MWFLO);
    short* enc_wf_hi  = (short*)(ws + OFF_EWFHI);
    short* enc_wf_lo  = (short*)(ws + OFF_EWFLO);
    short* hbm_hi     = (short*)(ws + OFF_HBMHI);
    short* hbm_lo     = (short*)(ws + OFF_HBMLO);
    short* hbe_hi     = (short*)(ws + OFF_HBEHI);
    short* hbe_lo     = (short*)(ws + OFF_HBELO);
    float* img_hidden = ws + OFF_IMGH;
    float* lang_in    = ws + OFF_LANGIN;
    float* enc_xW     = ws + OFF_ENCXW;
    float* enc_hs     = ws + OFF_ENCHS;
    float* lang_h     = ws + OFF_LANGH;
    float* hidden     = ws + OFF_HIDDEN;
    float* mem_xW     = ws + OFF_MEMXW;
    float* mem_hs     = ws + OFF_MEMHS;
    float* enc_bc     = ws + OFF_ENCBC;
    float* mem_bc     = ws + OFF_MEMBC;
    float* head_w     = ws + OFF_HEADW;
    float* head_b     = ws + OFF_HEADB;
    unsigned* bars    = (unsigned*)(ws + OFF_BARS);

    prep_kernel<<<64, 256, 0, stream>>>(enc_bih, enc_bhh, mem_bih, mem_bhh,
                                        actor_w, actor_b, critic_w, critic_b,
                                        enc_bc, mem_bc, head_w, head_b, bars);
    conv_kernel<<<TBTOT, 256, 0, stream>>>(x_img, conv1_w, conv1_b, conv2_w, conv2_b,
                                           conv3_w, conv3_b, conv3_flat);
    gemm64<true><<<dim3(128, 4), 64, 0, stream>>>(conv3_flat, fc_w, fc_b, img_hidden, TBTOT, 256, 1568);
    // conv3 region dead from here; build LSTM split-weight fragments in it
    split_frag_kernel<<<65536, 256, 0, stream>>>(mem_Whh, mem_wf_hi, mem_wf_lo, 1024);
    split_frag_kernel<<<4096, 256, 0, stream>>>(enc_Whh, enc_wf_hi, enc_wf_lo, 256);
    embed_kernel<<<1024, 256, 0, stream>>>(x_lang, emb, lang_in);
    gemm64<false><<<dim3(128, 16), 64, 0, stream>>>(lang_in, enc_Wih, enc_bc, enc_xW, TBTOT, 1024, 32);
    lstm_mfma_kernel<256, false><<<dim3(16, 4), 256, 0, stream>>>(
        enc_xW, enc_wf_hi, enc_wf_lo, done, enc_h0, enc_c0, hbe_hi, hbe_lo, enc_hs,
        bars + 0, 8u);
    gemm64<true><<<dim3(128, 1), 64, 0, stream>>>(enc_hs, lemb_w, lemb_b, lang_h, TBTOT, 32, 256);
    concat_kernel<<<TBTOT, 288, 0, stream>>>(img_hidden, lang_h, hidden);
    gemm64<false><<<dim3(128, 64), 64, 0, stream>>>(hidden, mem_Wih, mem_bc, mem_xW, TBTOT, 4096, 288);
    lstm_mfma_kernel<1024, true><<<dim3(64, 4), 256, 0, stream>>>(
        mem_xW, mem_wf_hi, mem_wf_lo, done, mem_h0, mem_c0, hbm_hi, hbm_lo, mem_hs,
        bars + 160, 32u);
    gemm64<false><<<dim3(128, 1), 64, 0, stream>>>(mem_hs, head_w, head_b, (float*)d_out, TBTOT, 16, 1024);
}